// Round 13
// baseline (206.767 us; speedup 1.0000x reference)
//
#include <hip/hip_runtime.h>
#include <math.h>

#define L 384
#define CA 128
#define NH 8
#define HD 16
#define NB 6
#define NS 2
#define NP (L*L)   // 147456

typedef __attribute__((ext_vector_type(4))) float f32x4;
typedef __attribute__((ext_vector_type(8))) short s16x8;
typedef __attribute__((ext_vector_type(4))) unsigned short u16x4;
typedef unsigned short ushort_t;

__device__ inline unsigned short f2bf(float f){
  union { float f; unsigned int u; } v; v.f = f;
  unsigned int u = v.u;
  unsigned int r = u + 0x7FFF + ((u>>16)&1);
  return (unsigned short)(r>>16);
}
__device__ inline float bf2f(ushort_t u){
  union { float f; unsigned int i; } v; v.i = ((unsigned int)u)<<16; return v.f;
}

#define WT_LAYER 196608

// ---------------------------------------------------------------------------
// K_pre0: 1 block. wzT [48][128] bf16, rbase[128], cb[48].
// ---------------------------------------------------------------------------
__global__ __launch_bounds__(256) void k_pre0(
    const float* zng, const float* znb, const float* zw, const float* zb,
    const float* relp_w, const float* relp_b,
    ushort_t* wzT, float* rbase, float* cb){
  int t = threadIdx.x;
  __shared__ float part[48][5];
  for(int idx=t; idx<6144; idx+=256){
    int h = idx>>7, c = idx&127;
    wzT[h*128+c] = f2bf(zng[(h>>3)*128+c]*zw[((h>>3)*128+c)*8+(h&7)]);
  }
  if(t<128) rbase[t] = relp_w[132*128+t] + relp_w[135*128+t] + relp_b[t];
  if(t<192){
    int h = t>>2, ch = t&3, blk = h>>3, hh = h&7;
    float acc = 0.f;
    #pragma unroll 8
    for(int c=ch*32; c<ch*32+32; c++)
      acc += znb[blk*128+c]*zw[(blk*128+c)*8+hh];
    part[h][ch] = acc;
  }
  __syncthreads();
  if(t<48) cb[t] = zb[t] + part[t][0]+part[t][1]+part[t][2]+part[t][3];
}

// ---------------------------------------------------------------------------
// K_mega: 2640 blocks x 256.
//   bid <2304 : pair-bias, BARRIER-FREE: each wave owns 16 pairs end-to-end
//               (direct global z reads, per-wave LDS transpose slice)
//   bid <2628 : weight transpose tiles
//   bid <2640 : t_feat
// ---------------------------------------------------------------------------
__global__ __launch_bounds__(256) void k_mega(
    const float* z_trunk, const float* relp_w, const float* rbase,
    const ushort_t* wzT, const float* cb, ushort_t* bias_all,
    const float* qw, const float* kw, const float* vw,
    const float* f1w, const float* f2w, const float* ow,
    const float* s_in_w, const float* s2a_w,
    ushort_t* wT, ushort_t* s_in_wT, ushort_t* s2a_wT,
    const float* sigma, const float* t1w, const float* t1b,
    const float* t2w, const float* t2b, float* t_feat){
  __shared__ float smem[4160];   // 16.6 KB shared across paths
  int bid = blockIdx.x, t = threadIdx.x;

  if(bid < 2304){
    // ================= pair bias (no block barriers) =================
    int lane = t&63, wv = t>>6;
    int rowf = lane&15, kg = lane>>4;
    int p0 = bid*64 + wv*16;           // wave's 16 consecutive pairs
    int p = p0 + rowf;
    int i = p/L, j = p - i*L, d = i - j;
    int r1 = d+32; r1 = r1<0?0:(r1>64?64:r1);
    int r2 = (d==0) ? 98 : 131;
    const float* zp  = z_trunk + (size_t)p*128;
    const float* w1p = relp_w + r1*128;
    const float* w2p = relp_w + r2*128;

    float val[4][8];
    float s = 0.f;
    #pragma unroll
    for(int ks=0; ks<4; ks++){
      int c0 = ks*32 + kg*8;
      f32x4 za = *(const f32x4*)(zp +c0), zb2 = *(const f32x4*)(zp +c0+4);
      f32x4 wa = *(const f32x4*)(w1p+c0), wb = *(const f32x4*)(w1p+c0+4);
      f32x4 ua = *(const f32x4*)(w2p+c0), ub = *(const f32x4*)(w2p+c0+4);
      f32x4 ra = *(const f32x4*)(rbase+c0), rb = *(const f32x4*)(rbase+c0+4);
      #pragma unroll
      for(int jj=0;jj<4;jj++){
        val[ks][jj]   = za[jj]+wa[jj]+ua[jj]+ra[jj];
        val[ks][jj+4] = zb2[jj]+wb[jj]+ub[jj]+rb[jj];
        s += val[ks][jj] + val[ks][jj+4];
      }
    }
    s += __shfl_xor(s,16,64); s += __shfl_xor(s,32,64);
    float mean = s*(1.f/128.f);
    float q2 = 0.f;
    #pragma unroll
    for(int ks=0; ks<4; ks++)
      #pragma unroll
      for(int jj=0;jj<8;jj++){ float dd = val[ks][jj]-mean; q2 += dd*dd; }
    q2 += __shfl_xor(q2,16,64); q2 += __shfl_xor(q2,32,64);
    float rstd = rsqrtf(q2*(1.f/128.f) + 1e-5f);

    s16x8 af[4];
    #pragma unroll
    for(int ks=0; ks<4; ks++)
      #pragma unroll
      for(int jj=0;jj<8;jj++) af[ks][jj] = (short)f2bf((val[ks][jj]-mean)*rstd);

    float* myc = smem + wv*816;        // per-wave 48x17 slice
    #pragma unroll
    for(int ht=0; ht<3; ht++){
      int col = ht*16 + rowf;
      float cbv = cb[col];
      f32x4 acc = {cbv,cbv,cbv,cbv};
      #pragma unroll
      for(int ks=0; ks<4; ks++){
        s16x8 bf = *(const s16x8*)&wzT[col*128 + ks*32 + kg*8];
        acc = __builtin_amdgcn_mfma_f32_16x16x32_bf16(af[ks], bf, acc, 0,0,0);
      }
      #pragma unroll
      for(int i2=0;i2<4;i2++) myc[col*17 + kg*4 + i2] = acc[i2];
    }
    // same-wave LDS write->read: compiler lgkmcnt orders it, no barrier
    int i0 = p0/L, qt_ = i0>>4, q16 = i0&15, j0 = p0 - i0*L;
    #pragma unroll
    for(int it=0; it<12; it++){
      int idx = lane + it*64;
      int pl = idx>>4, c = idx&15;       // pl = li*8+h
      int li_ = pl>>3, h_ = pl&7;
      bias_all[(size_t)((li_*24+qt_)*8+h_)*6144 + q16*384 + j0 + c] =
          f2bf(myc[pl*17 + c]);
    }
  } else if(bid < 2628){
    // ================= weight transposes =================
    float (*tl)[65] = (float(*)[65])smem;
    int b = bid - 2304;
    const float* src; ushort_t* dst;
    int M, N, k0, n0;
    if(b < 96){
      int mat = b>>2, li = mat>>2, wsel = mat&3, tile = b&3;
      const float* const ws_[4] = {qw, kw, vw, ow};
      const int off_[4] = {0, 16384, 32768, 180224};
      src = ws_[wsel] + (size_t)li*16384;
      dst = wT + (size_t)li*WT_LAYER + off_[wsel];
      M = 128; N = 128; k0 = (tile>>1)*64; n0 = (tile&1)*64;
    } else if(b < 192){
      int idx = b-96, li = idx>>4, tile = idx&15;
      src = f1w + (size_t)li*65536;
      dst = wT + (size_t)li*WT_LAYER + 49152;
      M = 128; N = 512; k0 = (tile>>3)*64; n0 = (tile&7)*64;
    } else if(b < 288){
      int idx = b-192, li = idx>>4, tile = idx&15;
      src = f2w + (size_t)li*65536;
      dst = wT + (size_t)li*WT_LAYER + 114688;
      M = 512; N = 128; k0 = (tile>>1)*64; n0 = (tile&1)*64;
    } else if(b < 312){
      int tile = b-288;
      src = s_in_w; dst = s_in_wT;
      M = 256; N = 384; k0 = (tile/6)*64; n0 = (tile%6)*64;
    } else {
      int tile = b-312;
      src = s2a_w; dst = s2a_wT;
      M = 384; N = 128; k0 = (tile>>1)*64; n0 = (tile&1)*64;
    }
    float v[16];
    #pragma unroll
    for(int it=0;it<16;it++){
      int i = t + it*256;
      v[it] = src[(size_t)(k0+(i>>6))*N + n0+(i&63)];
    }
    #pragma unroll
    for(int it=0;it<16;it++){
      int i = t + it*256;
      tl[i>>6][i&63] = v[it];
    }
    __syncthreads();
    #pragma unroll
    for(int it=0;it<16;it++){
      int i = t + it*256;
      dst[(size_t)(n0+(i>>6))*M + k0+(i&63)] = f2bf(tl[i&63][i>>6]);
    }
  } else {
    // ================= t_feat (12 blocks) =================
    int j = bid - 2628;
    int s = j/6, c0 = (j%6)*64;
    float sg = sigma[s];
    for(int i=t; i<384; i+=256){
      float x = sg*t1w[i] + t1b[i];
      smem[i] = x / (1.f + expf(-x));
    }
    __syncthreads();
    int col = c0 + (t&63), ch = t>>6;
    float acc = 0.f;
    #pragma unroll 8
    for(int k=ch*96; k<ch*96+96; k++)
      acc += smem[k]*t2w[(size_t)k*384+col];
    smem[384 + ch*64 + (t&63)] = acc;
    __syncthreads();
    if(t<64)
      t_feat[s*384 + c0 + t] = t2b[c0+t]
        + smem[384+t] + smem[448+t] + smem[512+t] + smem[576+t];
  }
}

// ---------------------------------------------------------------------------
// QKV projection from zh (4-wave version for k_qkv0)
// ---------------------------------------------------------------------------
__device__ inline void qkv_project(ushort_t zh[16][152], const ushort_t* wTl,
                                   const float* qb, const float* kb, const float* vb,
                                   ushort_t* q_bf, ushort_t* k_bf, ushort_t* vT_bf,
                                   int s_idx, int lbase, int wv, int rowf, int kg){
  s16x8 af[4];
  #pragma unroll
  for(int ks=0;ks<4;ks++) af[ks] = *(const s16x8*)&zh[rowf][ks*32 + kg*8];
  #pragma unroll
  for(int u=0;u<6;u++){
    int unit = wv*6 + u;
    int proj = unit>>3, nt = unit&7;
    int col = nt*16 + rowf;
    const ushort_t* wp = wTl + proj*16384;
    const float* bias = proj==0? qb : (proj==1? kb : vb);
    float bv = bias[col];
    f32x4 acc = {bv,bv,bv,bv};
    #pragma unroll
    for(int ks=0;ks<4;ks++){
      s16x8 bf = *(const s16x8*)&wp[col*128 + ks*32 + kg*8];
      acc = __builtin_amdgcn_mfma_f32_16x16x32_bf16(af[ks], bf, acc, 0,0,0);
    }
    int sh = s_idx*NH + nt;
    if(proj==2){
      #pragma unroll
      for(int i2=0;i2<4;i2++)
        vT_bf[((size_t)sh*16 + rowf)*384 + lbase + kg*4 + i2] = f2bf(acc[i2]);
    } else {
      float sc = (proj==0)? 0.25f : 1.0f;
      ushort_t* outp = (proj==0)? q_bf : k_bf;
      #pragma unroll
      for(int i2=0;i2<4;i2++)
        outp[((size_t)sh*384 + lbase + kg*4 + i2)*16 + rowf] = f2bf(acc[i2]*sc);
    }
  }
}

// ---------------------------------------------------------------------------
// K_qkv0: a_init + LN + layer-0 QKV. 48 blocks x 256.
// ---------------------------------------------------------------------------
__global__ __launch_bounds__(256) void k_qkv0(
    const float* x_t, const float* s_inputs, const float* s_trunk,
    const float* s_in_b, const ushort_t* s_in_wT,
    const float* s2a_b, const ushort_t* s2a_wT,
    const float* xp_w, const float* xp_b, const float* t_feat,
    const float* g, const float* bb,
    const ushort_t* wTl, const float* qb, const float* kb, const float* vb,
    float* a2, ushort_t* q_bf, ushort_t* k_bf, ushort_t* vT_bf){
  __shared__ ushort_t si[16][280];
  __shared__ ushort_t scb[16][408];
  __shared__ float xrow[16][21];
  __shared__ float a_new[16][132];
  __shared__ ushort_t zh[16][152];
  int t = threadIdx.x, lane = t&63, wv = t>>6;
  int rowf = lane&15, kg = lane>>4;
  int bid = blockIdx.x, s_idx = bid/24, lt = bid%24;
  int lr0 = lt*16;

  for(int i=t;i<16*256;i+=256){
    int r=i>>8, c=i&255;
    si[r][c] = f2bf(s_inputs[(size_t)(lr0+r)*256+c]);
  }
  for(int i=t;i<16*21;i+=256){
    int r=i/21, u=i%21;
    xrow[r][u] = x_t[((size_t)s_idx*L + lr0 + r)*21 + u];
  }
  __syncthreads();

  {
    s16x8 af1[8];
    #pragma unroll
    for(int ks=0;ks<8;ks++) af1[ks] = *(const s16x8*)&si[rowf][ks*32+kg*8];
    const float* tf = t_feat + s_idx*384;
    #pragma unroll
    for(int nn=0;nn<6;nn++){
      int col = (wv*6+nn)*16 + rowf;
      float bv = s_in_b[col];
      f32x4 acc = {bv,bv,bv,bv};
      #pragma unroll
      for(int ks=0;ks<8;ks++){
        s16x8 bf = *(const s16x8*)&s_in_wT[col*256 + ks*32 + kg*8];
        acc = __builtin_amdgcn_mfma_f32_16x16x32_bf16(af1[ks], bf, acc, 0,0,0);
      }
      float tfc = tf[col];
      #pragma unroll
      for(int i2=0;i2<4;i2++){
        int r = kg*4+i2;
        scb[r][col] = f2bf(acc[i2] + s_trunk[(size_t)(lr0+r)*384+col] + tfc);
      }
    }
  }
  __syncthreads();

  {
    s16x8 xf[12];
    #pragma unroll
    for(int ks=0;ks<12;ks++) xf[ks] = *(const s16x8*)&scb[rowf][ks*32+kg*8];
    #pragma unroll
    for(int nn=0;nn<2;nn++){
      int col = (wv*2+nn)*16 + rowf;
      float base = xp_b[col] + s2a_b[col];
      f32x4 acc;
      #pragma unroll
      for(int i2=0;i2<4;i2++){
        float xc = base;
        #pragma unroll
        for(int u=0;u<21;u++) xc += xrow[kg*4+i2][u]*xp_w[u*128+col];
        acc[i2] = xc;
      }
      #pragma unroll
      for(int ks=0;ks<12;ks++){
        s16x8 bf = *(const s16x8*)&s2a_wT[col*384 + ks*32 + kg*8];
        acc = __builtin_amdgcn_mfma_f32_16x16x32_bf16(xf[ks], bf, acc, 0,0,0);
      }
      #pragma unroll
      for(int i2=0;i2<4;i2++){
        int r = kg*4+i2;
        a_new[r][col] = acc[i2];
        a2[((size_t)(s_idx*L + lr0 + r))*128 + col] = acc[i2];
      }
    }
  }
  __syncthreads();

  {
    int row = t>>4, sub = t&15;
    const float* xp = &a_new[row][sub*8];
    f32x4 x0 = *(const f32x4*)xp;
    f32x4 x1 = *(const f32x4*)(xp+4);
    float s = x0[0]+x0[1]+x0[2]+x0[3]+x1[0]+x1[1]+x1[2]+x1[3];
    s += __shfl_xor(s,1,64); s += __shfl_xor(s,2,64);
    s += __shfl_xor(s,4,64); s += __shfl_xor(s,8,64);
    float mean = s*(1.f/128.f);
    float q2 = 0.f;
    #pragma unroll
    for(int jj=0;jj<4;jj++){ float d0=x0[jj]-mean, d1=x1[jj]-mean; q2 += d0*d0+d1*d1; }
    q2 += __shfl_xor(q2,1,64); q2 += __shfl_xor(q2,2,64);
    q2 += __shfl_xor(q2,4,64); q2 += __shfl_xor(q2,8,64);
    float rstd = rsqrtf(q2*(1.f/128.f)+1e-5f);
    int c0 = sub*8;
    f32x4 g0 = *(const f32x4*)(g+c0), g1 = *(const f32x4*)(g+c0+4);
    f32x4 b0 = *(const f32x4*)(bb+c0), b1 = *(const f32x4*)(bb+c0+4);
    s16x8 pack;
    #pragma unroll
    for(int jj=0;jj<4;jj++){
      pack[jj]   = (short)f2bf((x0[jj]-mean)*rstd*g0[jj]+b0[jj]);
      pack[jj+4] = (short)f2bf((x1[jj]-mean)*rstd*g1[jj]+b1[jj]);
    }
    *(s16x8*)&zh[row][c0] = pack;
  }
  __syncthreads();
  qkv_project(zh, wTl, qb, kb, vb, q_bf, k_bf, vT_bf, s_idx, lr0, wv, rowf, kg);
}

// ---------------------------------------------------------------------------
// K_fused: 1024 threads / 16 waves. Wave-private bias staging (no barrier
// before flash). flash -> o-proj -> LN -> FFN -> next-QKV / out.
// ---------------------------------------------------------------------------
__global__ __launch_bounds__(1024) void k_fused(
    float* a2, const float* an_g, const float* an_b, const ushort_t* wT,
    const float* qb_all, const float* kb_all, const float* vb_all,
    const float* ob_all, const float* f1b_all, const float* f2b_all,
    ushort_t* q_bf, ushort_t* k_bf, ushort_t* vT_bf,
    const ushort_t* bias_all, const float* out_w, const float* out_b,
    float* out, int li){
  __shared__ float orow[16][132];
  __shared__ float ocomb[8][16][20];
  __shared__ float lcomb[8][16];
  union SM {
    struct {
      ushort_t biasw[16][16][200];   // 102,400 B (per-wave slices)
      ushort_t P[16][16][72];        //  36,864 B
    } fl;
    struct {
      float a_new[16][132];
      ushort_t zh[16][152];
      ushort_t h_lds[16][536];
      float fcomb[8][16][20];
    } post;
  };
  __shared__ SM sm;

  int t = threadIdx.x, lane = t&63, wv = t>>6;
  int rowf = lane&15, kg = lane>>4;
  int bid = blockIdx.x, s_idx = bid/24, qt = bid%24;
  int r0 = bid*16;
  const ushort_t* wTl = wT + (size_t)li*WT_LAYER;
  const float* g  = an_g + li*128;
  const float* bb = an_b + li*128;

  // ---- flash: wave = (head h, key-half kh); wave-private bias staging ----
  {
    int h = wv>>1, kh = wv&1;
    int sh = s_idx*NH + h;
    {
      const ushort_t* btile = bias_all + (size_t)(li*24+qt)*8*6144
                            + (size_t)h*16*384 + kh*192;
      #pragma unroll
      for(int it=0; it<6; it++){
        int idx = lane + it*64;
        int row = idx/24, seg = idx%24;
        *(s16x8*)&sm.fl.biasw[wv][row][seg*8] =
            *(const s16x8*)&btile[(size_t)row*384 + seg*8];
      }
    }
    ushort_t (*Pw)[72] = sm.fl.P[wv];
    s16x8 qf = {0,0,0,0,0,0,0,0};
    if(kg < 2) qf = *(const s16x8*)&q_bf[((size_t)sh*384 + qt*16 + rowf)*16 + kg*8];
    const ushort_t* kp = k_bf + (size_t)sh*384*16;
    const ushort_t* vp = vT_bf + ((size_t)sh*16 + rowf)*384;

    f32x4 o0 = {0,0,0,0}, o1 = {0,0,0,0};
    float l_acc = 0.f;
    for(int c=0;c<3;c++){
      int key0 = kh*192 + c*64;
      f32x4 st[4];
      #pragma unroll
      for(int t4=0;t4<4;t4++){
        s16x8 kf = {0,0,0,0,0,0,0,0};
        if(kg < 2) kf = *(const s16x8*)&kp[((size_t)(key0 + t4*16 + rowf))*16 + kg*8];
        u16x4 bb4 = *(const u16x4*)&sm.fl.biasw[wv][rowf][c*64 + t4*16 + kg*4];
        f32x4 cin;
        #pragma unroll
        for(int jj=0;jj<4;jj++) cin[jj] = bf2f(bb4[jj]);
        st[t4] = __builtin_amdgcn_mfma_f32_16x16x32_bf16(kf, qf, cin, 0,0,0);
      }
      #pragma unroll
      for(int t4=0;t4<4;t4++){
        float p0 = __expf(st[t4][0]), p1 = __expf(st[t4][1]);
        float p2 = __expf(st[t4][2]), p3 = __expf(st[t4][3]);
        l_acc += (p0+p1)+(p2+p3);
        u16x4 pk = {f2bf(p0), f2bf(p1), f2bf(p2), f2bf(p3)};
        *(u16x4*)&Pw[rowf][t4*16 + kg*4] = pk;
      }
      {
        s16x8 pa = *(const s16x8*)&Pw[rowf][kg*8];
        s16x8 vbf = *(const s16x8*)&vp[key0 + kg*8];
        o0 = __builtin_amdgcn_mfma_f32_16x16x32_bf16(pa, vbf, o0, 0,0,0);
        s16x8 pb = *(const s16x8*)&Pw[rowf][32 + kg*8];
        s16x8 vbf2 = *(const s16x8*)&vp[key0 + 32 + kg*8];
        o1 = __builtin_amdgcn_mfma_f32_16x16x32_bf16(pb, vbf2, o1, 0,0,0);
      }
    }
    f32x4 o_acc = o0 + o1;
    l_acc += __shfl_xor(l_acc, 16, 64);
    l_acc += __shfl_xor(l_acc, 32, 64);
    if(kh==1){
      #pragma unroll
      for(int i2=0;i2<4;i2++) ocomb[h][kg*4+i2][rowf] = o_acc[i2];
      if(kg==0) lcomb[h][rowf] = l_acc;
    }
    __syncthreads();
    if(kh==0){
      l_acc += lcomb[h][rowf];
      #pragma unroll
      for(int i2=0;i2<4;i2++) o_acc[i2] += ocomb[h][kg*4+i2][rowf];
      float inv = 1.f / l_acc;
      #pragma unroll
      for(int i2=0;i2<4;i2++){
        float invq = __shfl(inv, kg*4 + i2, 64);
        orow[kg*4+i2][h*16 + rowf] = o_acc[i2]*invq;
      }
    }
  }
  __syncthreads();

  // ---- o-proj + residual -> a_new (waves 0..7) ----
  if(wv < 8){
    s16x8 af[4];
    #pragma unroll
    for(int ks=0;ks<4;ks++){
      f32x4 v0 = *(const f32x4*)&orow[rowf][ks*32+kg*8];
      f32x4 v1 = *(const f32x4*)&orow[rowf][ks*32+kg*8+4];
      s16x8 p;
      #pragma unroll
      for(int jj=0;jj<4;jj++){ p[jj] = (short)f2bf(v0[jj]); p[jj+4] = (short)f2bf(v1[jj]); }
      af[ks] = p;
    }
    const ushort_t* wo = wTl + 180224;
    const float* obp = ob_all + li*128;
    int col = wv*16 + rowf;
    float bv = obp[col];
    f32x4 acc = {bv,bv,bv,bv};
    f32x4 accB = {0,0,0,0};
    #pragma unroll
    for(int ks=0;ks<2;ks++){
      s16x8 bf = *(const s16x8*)&wo[col*128 + ks*32 + kg*8];
      acc = __builtin_amdgcn_mfma_f32_16x16x32_bf16(af[ks], bf, acc, 0,0,0);
      s16x8 bf2 = *(const s16x8*)&wo[col*128 + (ks+2)*32 + kg*8];
      accB = __builtin_amdgcn_mfma_f32_16x16x32_bf16(af[ks+2], bf2, accB, 0,0,0);
    }
    acc += accB;
    #pragma unroll
    for(int i2=0;i2<4;i2++){
      int r = kg*4+i2;
      sm.post.a_new[r][col] = a2[(size_t)(r0+r)*128 + col] + acc[i2];
    }
  }
  __syncthreads();

  // ---- LN (wave wv owns row wv) ----
  {
    int row = wv, c0 = lane*2;
    float x0 = sm.post.a_new[row][c0], x1 = sm.post.a_new[row][c0+1];
    float s = x0+x1;
    s += __shfl_xor(s,1,64); s += __shfl_xor(s,2,64); s += __shfl_xor(s,4,64);
    s += __shfl_xor(s,8,64); s += __shfl_xor(s,16,64); s += __shfl_xor(s,32,64);
    float mean = s*(1.f/128.f);
    float d0=x0-mean, d1=x1-mean;
    float q2 = d0*d0+d1*d1;
    q2 += __shfl_xor(q2,1,64); q2 += __shfl_xor(q2,2,64); q2 += __shfl_xor(q2,4,64);
    q2 += __shfl_xor(q2,8,64); q2 += __shfl_xor(q2,16,64); q2 += __shfl_xor(q2,32,64);
    float rstd = rsqrtf(q2*(1.f/128.f)+1e-5f);
    unsigned int pk = (unsigned int)f2bf(d0*rstd*g[c0]+bb[c0])
                    | ((unsigned int)f2bf(d1*rstd*g[c0+1]+bb[c0+1])<<16);
    *(unsigned int*)&sm.post.zh[row][c0] = pk;
  }
  __syncthreads();

  // ---- FFN GEMM1 + gelu ----
  {
    s16x8 xf[4];
    #pragma unroll
    for(int ks=0;ks<4;ks++) xf[ks] = *(const s16x8*)&sm.post.zh[rowf][ks*32 + kg*8];
    const ushort_t* w1 = wTl + 49152;
    const float* f1bp = f1b_all + li*512;
    #pragma unroll
    for(int nn=0; nn<2; nn++){
      int col = (wv*2+nn)*16 + rowf;
      float bv = f1bp[col];
      f32x4 acc = {bv,bv,bv,bv};
      #pragma unroll
      for(int ks=0;ks<4;ks++){
        s16x8 bf = *(const s16x8*)&w1[col*128 + ks*32 + kg*8];
        acc = __builtin_amdgcn_mfma_f32_16x16x32_bf16(xf[ks], bf, acc, 0,0,0);
      }
      #pragma unroll
      for(int i2=0;i2<4;i2++){
        float x = acc[i2];
        float ge = 0.5f*x*(1.f + erff(x*0.70710678f));
        sm.post.h_lds[kg*4+i2][col] = f2bf(ge);
      }
    }
  }
  __syncthreads();

  // ---- FFN GEMM2 ----
  {
    const ushort_t* w2 = wTl + 114688;
    const float* f2bp = f2b_all + li*128;
    int ct = wv>>1, kh2 = wv&1;
    int col2 = ct*16 + rowf;
    float bv = kh2? 0.f : f2bp[col2];
    f32x4 accA = {bv,bv,bv,bv};
    f32x4 accB = {0,0,0,0};
    int ks0 = kh2*8;
    #pragma unroll
    for(int kk=0; kk<4; kk++){
      s16x8 hfA = *(const s16x8*)&sm.post.h_lds[rowf][(ks0+kk)*32 + kg*8];
      s16x8 bfA = *(const s16x8*)&w2[col2*512 + (ks0+kk)*32 + kg*8];
      accA = __builtin_amdgcn_mfma_f32_16x16x32_bf16(hfA, bfA, accA, 0,0,0);
      s16x8 hfB = *(const s16x8*)&sm.post.h_lds[rowf][(ks0+kk+4)*32 + kg*8];
      s16x8 bfB = *(const s16x8*)&w2[col2*512 + (ks0+kk+4)*32 + kg*8];
      accB = __builtin_amdgcn_mfma_f32_16x16x32_bf16(hfB, bfB, accB, 0,0,0);
    }
    accA += accB;
    if(kh2==1){
      #pragma unroll
      for(int i2=0;i2<4;i2++) sm.post.fcomb[ct][kg*4+i2][rowf] = accA[i2];
    }
    __syncthreads();
    if(kh2==0){
      #pragma unroll
      for(int i2=0;i2<4;i2++){
        int r = kg*4+i2;
        float fin = sm.post.a_new[r][col2] + accA[i2] + sm.post.fcomb[ct][r][rowf];
        a2[(size_t)(r0+r)*128 + col2] = fin;
        sm.post.a_new[r][col2] = fin;
      }
    }
  }
  __syncthreads();

  if(li < NB-1){
    const float* g2  = an_g + (li+1)*128;
    const float* bb2 = an_b + (li+1)*128;
    {
      int row = wv, c0 = lane*2;
      float x0 = sm.post.a_new[row][c0], x1 = sm.post.a_new[row][c0+1];
      float s = x0+x1;
      s += __shfl_xor(s,1,64); s += __shfl_xor(s,2,64); s += __shfl_xor(s,4,64);
      s += __shfl_xor(s,8,64); s += __shfl_xor(s,16,64); s += __shfl_xor(s,32,64);
      float mean = s*(1.f/128.f);
      float d0=x0-mean, d1=x1-mean;
      float q2 = d0*d0+d1*d1;
      q2 += __shfl_xor(q2,1,64); q2 += __shfl_xor(q2,2,64); q2 += __shfl_xor(q2,4,64);
      q2 += __shfl_xor(q2,8,64); q2 += __shfl_xor(q2,16,64); q2 += __shfl_xor(q2,32,64);
      float rstd = rsqrtf(q2*(1.f/128.f)+1e-5f);
      unsigned int pk = (unsigned int)f2bf(d0*rstd*g2[c0]+bb2[c0])
                      | ((unsigned int)f2bf(d1*rstd*g2[c0+1]+bb2[c0+1])<<16);
      *(unsigned int*)&sm.post.zh[row][c0] = pk;
    }
    __syncthreads();
    {
      const ushort_t* wTn = wT + (size_t)(li+1)*WT_LAYER;
      const float* qb2 = qb_all + (li+1)*128;
      const float* kb2 = kb_all + (li+1)*128;
      const float* vb2 = vb_all + (li+1)*128;
      s16x8 af[4];
      #pragma unroll
      for(int ks=0;ks<4;ks++) af[ks] = *(const s16x8*)&sm.post.zh[rowf][ks*32 + kg*8];
      #pragma unroll
      for(int u=0;u<2;u++){
        int unit = wv + u*16;
        if(unit < 24){
          int proj = unit>>3, nt = unit&7;
          int col = nt*16 + rowf;
          const ushort_t* wp = wTn + proj*16384;
          const float* bias = proj==0? qb2 : (proj==1? kb2 : vb2);
          float bv = bias[col];
          f32x4 acc = {bv,bv,bv,bv};
          #pragma unroll
          for(int ks=0;ks<4;ks++){
            s16x8 bf = *(const s16x8*)&wp[col*128 + ks*32 + kg*8];
            acc = __builtin_amdgcn_mfma_f32_16x16x32_bf16(af[ks], bf, acc, 0,0,0);
          }
          int sh = s_idx*NH + nt;
          if(proj==2){
            #pragma unroll
            for(int i2=0;i2<4;i2++)
              vT_bf[((size_t)sh*16 + rowf)*384 + qt*16 + kg*4 + i2] = f2bf(acc[i2]);
          } else {
            float sc = (proj==0)? 0.25f : 1.0f;
            ushort_t* outp = (proj==0)? q_bf : k_bf;
            #pragma unroll
            for(int i2=0;i2<4;i2++)
              outp[((size_t)sh*384 + qt*16 + kg*4 + i2)*16 + rowf] = f2bf(acc[i2]*sc);
          }
        }
      }
    }
  } else {
    for(int idx=t; idx<336; idx+=1024){
      int r = idx/21, c = idx%21;
      float acc = out_b[c];
      #pragma unroll 8
      for(int kk=0;kk<128;kk++) acc += sm.post.a_new[r][kk]*out_w[kk*21+c];
      out[(size_t)(r0+r)*21 + c] = acc;
    }
  }
}

extern "C" void kernel_launch(void* const* d_in, const int* in_sizes, int n_in,
                              void* d_out, int out_size, void* d_ws, size_t ws_size,
                              hipStream_t stream){
  const float* x_t      = (const float*)d_in[0];
  const float* sigma    = (const float*)d_in[1];
  const float* s_inputs = (const float*)d_in[2];
  const float* s_trunk  = (const float*)d_in[3];
  const float* z_trunk  = (const float*)d_in[4];
  const float* s_in_w = (const float*)d_in[6];
  const float* s_in_b = (const float*)d_in[7];
  const float* relp_w = (const float*)d_in[8];
  const float* relp_b = (const float*)d_in[9];
  const float* t1_w = (const float*)d_in[10];
  const float* t1_b = (const float*)d_in[11];
  const float* t2_w = (const float*)d_in[12];
  const float* t2_b = (const float*)d_in[13];
  const float* xp_w = (const float*)d_in[14];
  const float* xp_b = (const float*)d_in[15];
  const float* s2a_w = (const float*)d_in[16];
  const float* s2a_b = (const float*)d_in[17];
  const float* out_w = (const float*)d_in[18];
  const float* out_b = (const float*)d_in[19];
  const float* an_g = (const float*)d_in[20];
  const float* an_b = (const float*)d_in[21];
  const float* zn_g = (const float*)d_in[22];
  const float* zn_b = (const float*)d_in[23];
  const float* qw = (const float*)d_in[24];
  const float* qb = (const float*)d_in[25];
  const float* kw = (const float*)d_in[26];
  const float* kb = (const float*)d_in[27];
  const float* vw = (const float*)d_in[28];
  const float* vb = (const float*)d_in[29];
  const float* zw = (const float*)d_in[30];
  const float* zb = (const float*)d_in[31];
  const float* ow = (const float*)d_in[32];
  const float* ob = (const float*)d_in[33];
  const float* f1w = (const float*)d_in[34];
  const float* f1b = (const float*)d_in[35];
  const float* f2w = (const float*)d_in[36];
  const float* f2b = (const float*)d_in[37];

  float* ws = (float*)d_ws;
  ushort_t* bias_all = (ushort_t*)ws;             // 48*147456 shorts (tile-major)
  float* cb     = ws + (size_t)24*NP;             // 48
  float* t_feat = cb + 48;                        // 768
  float* a2     = t_feat + 768;                   // 98304
  float* rbase  = a2 + (size_t)NS*L*CA;           // 128
  ushort_t* wT      = (ushort_t*)(rbase + 128);   // 6*196608
  ushort_t* wzT     = wT + (size_t)6*WT_LAYER;    // 6144
  ushort_t* q_bf    = wzT + 6144;                 // 98304
  ushort_t* k_bf    = q_bf + 98304;               // 98304
  ushort_t* vT_bf   = k_bf + 98304;               // 98304
  ushort_t* s_in_wT = vT_bf + 98304;              // 98304
  ushort_t* s2a_wT  = s_in_wT + 98304;            // 49152
  float* outp = (float*)d_out;

  k_pre0<<<1,256,0,stream>>>(zn_g,zn_b,zw,zb,relp_w,relp_b,wzT,rbase,cb);
  k_mega<<<2640,256,0,stream>>>(z_trunk,relp_w,rbase,wzT,cb,bias_all,
                                qw,kw,vw,f1w,f2w,ow,s_in_w,s2a_w,
                                wT,s_in_wT,s2a_wT,
                                sigma,t1_w,t1_b,t2_w,t2_b,t_feat);
  k_qkv0<<<48,256,0,stream>>>(x_t,s_inputs,s_trunk,s_in_b,s_in_wT,
                              s2a_b,s2a_wT,xp_w,xp_b,t_feat,
                              an_g, an_b, wT, qb, kb, vb,
                              a2, q_bf, k_bf, vT_bf);
  for(int i=0;i<NB;i++){
    k_fused<<<48,1024,0,stream>>>(a2, an_g, an_b, wT,
        qb, kb, vb, ob, f1b, f2b,
        q_bf, k_bf, vT_bf, bias_all,
        out_w, out_b, outp, i);
  }
}

// Round 14
// 198.840 us; speedup vs baseline: 1.0399x; 1.0399x over previous
//
#include <hip/hip_runtime.h>
#include <math.h>

#define L 384
#define CA 128
#define NH 8
#define HD 16
#define NB 6
#define NS 2
#define NP (L*L)   // 147456

typedef __attribute__((ext_vector_type(4))) float f32x4;
typedef __attribute__((ext_vector_type(8))) short s16x8;
typedef __attribute__((ext_vector_type(4))) unsigned short u16x4;
typedef unsigned short ushort_t;

__device__ inline unsigned short f2bf(float f){
  union { float f; unsigned int u; } v; v.f = f;
  unsigned int u = v.u;
  unsigned int r = u + 0x7FFF + ((u>>16)&1);
  return (unsigned short)(r>>16);
}
__device__ inline float bf2f(ushort_t u){
  union { float f; unsigned int i; } v; v.i = ((unsigned int)u)<<16; return v.f;
}

#define WT_LAYER 196608

// ---------------------------------------------------------------------------
// K_pre0: 1 block. wzT [48][128] bf16, rbase[128], cb[48].
// ---------------------------------------------------------------------------
__global__ __launch_bounds__(256) void k_pre0(
    const float* zng, const float* znb, const float* zw, const float* zb,
    const float* relp_w, const float* relp_b,
    ushort_t* wzT, float* rbase, float* cb){
  int t = threadIdx.x;
  __shared__ float part[48][5];
  for(int idx=t; idx<6144; idx+=256){
    int h = idx>>7, c = idx&127;
    wzT[h*128+c] = f2bf(zng[(h>>3)*128+c]*zw[((h>>3)*128+c)*8+(h&7)]);
  }
  if(t<128) rbase[t] = relp_w[132*128+t] + relp_w[135*128+t] + relp_b[t];
  if(t<192){
    int h = t>>2, ch = t&3, blk = h>>3, hh = h&7;
    float acc = 0.f;
    #pragma unroll 8
    for(int c=ch*32; c<ch*32+32; c++)
      acc += znb[blk*128+c]*zw[(blk*128+c)*8+hh];
    part[h][ch] = acc;
  }
  __syncthreads();
  if(t<48) cb[t] = zb[t] + part[t][0]+part[t][1]+part[t][2]+part[t][3];
}

// ---------------------------------------------------------------------------
// K_mega: 2640 blocks x 256. __launch_bounds__(256,4): allow 128 VGPR so the
// 8 cold z loads stay in flight (r13: VGPR=44 serialized them).
//   bid <2304 : pair-bias, barrier-free, per-wave LDS slice
//   bid <2628 : weight transpose tiles
//   bid <2640 : t_feat
// ---------------------------------------------------------------------------
__global__ __launch_bounds__(256, 4) void k_mega(
    const float* z_trunk, const float* relp_w, const float* rbase,
    const ushort_t* wzT, const float* cb, ushort_t* bias_all,
    const float* qw, const float* kw, const float* vw,
    const float* f1w, const float* f2w, const float* ow,
    const float* s_in_w, const float* s2a_w,
    ushort_t* wT, ushort_t* s_in_wT, ushort_t* s2a_wT,
    const float* sigma, const float* t1w, const float* t1b,
    const float* t2w, const float* t2b, float* t_feat){
  __shared__ float smem[4160];   // 16.6 KB shared across paths
  int bid = blockIdx.x, t = threadIdx.x;

  if(bid < 2304){
    // ================= pair bias (no block barriers, max load ILP) ========
    int lane = t&63, wv = t>>6;
    int rowf = lane&15, kg = lane>>4;
    int p0 = bid*64 + wv*16;
    int p = p0 + rowf;
    int i = p/L, j = p - i*L, d = i - j;
    int r1 = d+32; r1 = r1<0?0:(r1>64?64:r1);
    int r2 = (d==0) ? 98 : 131;
    const float* zp  = z_trunk + (size_t)p*128 + kg*8;

    // --- issue ALL 8 cold z loads first (HBM, independent) ---
    f32x4 z0a = *(const f32x4*)(zp+  0), z0b = *(const f32x4*)(zp+  4);
    f32x4 z1a = *(const f32x4*)(zp+ 32), z1b = *(const f32x4*)(zp+ 36);
    f32x4 z2a = *(const f32x4*)(zp+ 64), z2b = *(const f32x4*)(zp+ 68);
    f32x4 z3a = *(const f32x4*)(zp+ 96), z3b = *(const f32x4*)(zp+100);

    const float* w1p = relp_w + r1*128 + kg*8;
    const float* w2p = relp_w + r2*128 + kg*8;
    const float* rbp = rbase + kg*8;
    f32x4 c0a = *(const f32x4*)(w1p+  0) + *(const f32x4*)(w2p+  0) + *(const f32x4*)(rbp+  0);
    f32x4 c0b = *(const f32x4*)(w1p+  4) + *(const f32x4*)(w2p+  4) + *(const f32x4*)(rbp+  4);
    f32x4 c1a = *(const f32x4*)(w1p+ 32) + *(const f32x4*)(w2p+ 32) + *(const f32x4*)(rbp+ 32);
    f32x4 c1b = *(const f32x4*)(w1p+ 36) + *(const f32x4*)(w2p+ 36) + *(const f32x4*)(rbp+ 36);
    f32x4 c2a = *(const f32x4*)(w1p+ 64) + *(const f32x4*)(w2p+ 64) + *(const f32x4*)(rbp+ 64);
    f32x4 c2b = *(const f32x4*)(w1p+ 68) + *(const f32x4*)(w2p+ 68) + *(const f32x4*)(rbp+ 68);
    f32x4 c3a = *(const f32x4*)(w1p+ 96) + *(const f32x4*)(w2p+ 96) + *(const f32x4*)(rbp+ 96);
    f32x4 c3b = *(const f32x4*)(w1p+100) + *(const f32x4*)(w2p+100) + *(const f32x4*)(rbp+100);

    float val[4][8];
    float s = 0.f;
    #pragma unroll
    for(int jj=0;jj<4;jj++){
      val[0][jj]   = z0a[jj]+c0a[jj];  val[0][jj+4] = z0b[jj]+c0b[jj];
      val[1][jj]   = z1a[jj]+c1a[jj];  val[1][jj+4] = z1b[jj]+c1b[jj];
      val[2][jj]   = z2a[jj]+c2a[jj];  val[2][jj+4] = z2b[jj]+c2b[jj];
      val[3][jj]   = z3a[jj]+c3a[jj];  val[3][jj+4] = z3b[jj]+c3b[jj];
    }
    #pragma unroll
    for(int ks=0;ks<4;ks++)
      #pragma unroll
      for(int jj=0;jj<8;jj++) s += val[ks][jj];
    s += __shfl_xor(s,16,64); s += __shfl_xor(s,32,64);
    float mean = s*(1.f/128.f);
    float q2 = 0.f;
    #pragma unroll
    for(int ks=0; ks<4; ks++)
      #pragma unroll
      for(int jj=0;jj<8;jj++){ float dd = val[ks][jj]-mean; q2 += dd*dd; }
    q2 += __shfl_xor(q2,16,64); q2 += __shfl_xor(q2,32,64);
    float rstd = rsqrtf(q2*(1.f/128.f) + 1e-5f);

    s16x8 af[4];
    #pragma unroll
    for(int ks=0; ks<4; ks++)
      #pragma unroll
      for(int jj=0;jj<8;jj++) af[ks][jj] = (short)f2bf((val[ks][jj]-mean)*rstd);

    float* myc = smem + wv*816;        // per-wave 48x17 slice
    #pragma unroll
    for(int ht=0; ht<3; ht++){
      int col = ht*16 + rowf;
      float cbv = cb[col];
      f32x4 acc = {cbv,cbv,cbv,cbv};
      #pragma unroll
      for(int ks=0; ks<4; ks++){
        s16x8 bf = *(const s16x8*)&wzT[col*128 + ks*32 + kg*8];
        acc = __builtin_amdgcn_mfma_f32_16x16x32_bf16(af[ks], bf, acc, 0,0,0);
      }
      #pragma unroll
      for(int i2=0;i2<4;i2++) myc[col*17 + kg*4 + i2] = acc[i2];
    }
    // same-wave LDS write->read: compiler lgkmcnt orders it, no barrier
    int i0 = p0/L, qt_ = i0>>4, q16 = i0&15, j0 = p0 - i0*L;
    #pragma unroll
    for(int it=0; it<12; it++){
      int idx = lane + it*64;
      int pl = idx>>4, c = idx&15;       // pl = li*8+h
      int li_ = pl>>3, h_ = pl&7;
      bias_all[(size_t)((li_*24+qt_)*8+h_)*6144 + q16*384 + j0 + c] =
          f2bf(myc[pl*17 + c]);
    }
  } else if(bid < 2628){
    // ================= weight transposes =================
    float (*tl)[65] = (float(*)[65])smem;
    int b = bid - 2304;
    const float* src; ushort_t* dst;
    int M, N, k0, n0;
    if(b < 96){
      int mat = b>>2, li = mat>>2, wsel = mat&3, tile = b&3;
      const float* const ws_[4] = {qw, kw, vw, ow};
      const int off_[4] = {0, 16384, 32768, 180224};
      src = ws_[wsel] + (size_t)li*16384;
      dst = wT + (size_t)li*WT_LAYER + off_[wsel];
      M = 128; N = 128; k0 = (tile>>1)*64; n0 = (tile&1)*64;
    } else if(b < 192){
      int idx = b-96, li = idx>>4, tile = idx&15;
      src = f1w + (size_t)li*65536;
      dst = wT + (size_t)li*WT_LAYER + 49152;
      M = 128; N = 512; k0 = (tile>>3)*64; n0 = (tile&7)*64;
    } else if(b < 288){
      int idx = b-192, li = idx>>4, tile = idx&15;
      src = f2w + (size_t)li*65536;
      dst = wT + (size_t)li*WT_LAYER + 114688;
      M = 512; N = 128; k0 = (tile>>1)*64; n0 = (tile&1)*64;
    } else if(b < 312){
      int tile = b-288;
      src = s_in_w; dst = s_in_wT;
      M = 256; N = 384; k0 = (tile/6)*64; n0 = (tile%6)*64;
    } else {
      int tile = b-312;
      src = s2a_w; dst = s2a_wT;
      M = 384; N = 128; k0 = (tile>>1)*64; n0 = (tile&1)*64;
    }
    float v[16];
    #pragma unroll
    for(int it=0;it<16;it++){
      int i = t + it*256;
      v[it] = src[(size_t)(k0+(i>>6))*N + n0+(i&63)];
    }
    #pragma unroll
    for(int it=0;it<16;it++){
      int i = t + it*256;
      tl[i>>6][i&63] = v[it];
    }
    __syncthreads();
    #pragma unroll
    for(int it=0;it<16;it++){
      int i = t + it*256;
      dst[(size_t)(n0+(i>>6))*M + k0+(i&63)] = f2bf(tl[i&63][i>>6]);
    }
  } else {
    // ================= t_feat (12 blocks) =================
    int j = bid - 2628;
    int s = j/6, c0 = (j%6)*64;
    float sg = sigma[s];
    for(int i=t; i<384; i+=256){
      float x = sg*t1w[i] + t1b[i];
      smem[i] = x / (1.f + expf(-x));
    }
    __syncthreads();
    int col = c0 + (t&63), ch = t>>6;
    float acc = 0.f;
    #pragma unroll 8
    for(int k=ch*96; k<ch*96+96; k++)
      acc += smem[k]*t2w[(size_t)k*384+col];
    smem[384 + ch*64 + (t&63)] = acc;
    __syncthreads();
    if(t<64)
      t_feat[s*384 + c0 + t] = t2b[c0+t]
        + smem[384+t] + smem[448+t] + smem[512+t] + smem[576+t];
  }
}

// ---------------------------------------------------------------------------
// QKV projection from zh (4-wave version for k_qkv0)
// ---------------------------------------------------------------------------
__device__ inline void qkv_project(ushort_t zh[16][152], const ushort_t* wTl,
                                   const float* qb, const float* kb, const float* vb,
                                   ushort_t* q_bf, ushort_t* k_bf, ushort_t* vT_bf,
                                   int s_idx, int lbase, int wv, int rowf, int kg){
  s16x8 af[4];
  #pragma unroll
  for(int ks=0;ks<4;ks++) af[ks] = *(const s16x8*)&zh[rowf][ks*32 + kg*8];
  #pragma unroll
  for(int u=0;u<6;u++){
    int unit = wv*6 + u;
    int proj = unit>>3, nt = unit&7;
    int col = nt*16 + rowf;
    const ushort_t* wp = wTl + proj*16384;
    const float* bias = proj==0? qb : (proj==1? kb : vb);
    float bv = bias[col];
    f32x4 acc = {bv,bv,bv,bv};
    #pragma unroll
    for(int ks=0;ks<4;ks++){
      s16x8 bf = *(const s16x8*)&wp[col*128 + ks*32 + kg*8];
      acc = __builtin_amdgcn_mfma_f32_16x16x32_bf16(af[ks], bf, acc, 0,0,0);
    }
    int sh = s_idx*NH + nt;
    if(proj==2){
      #pragma unroll
      for(int i2=0;i2<4;i2++)
        vT_bf[((size_t)sh*16 + rowf)*384 + lbase + kg*4 + i2] = f2bf(acc[i2]);
    } else {
      float sc = (proj==0)? 0.25f : 1.0f;
      ushort_t* outp = (proj==0)? q_bf : k_bf;
      #pragma unroll
      for(int i2=0;i2<4;i2++)
        outp[((size_t)sh*384 + lbase + kg*4 + i2)*16 + rowf] = f2bf(acc[i2]*sc);
    }
  }
}

// ---------------------------------------------------------------------------
// K_qkv0: a_init + LN + layer-0 QKV. 48 blocks x 256.
// ---------------------------------------------------------------------------
__global__ __launch_bounds__(256) void k_qkv0(
    const float* x_t, const float* s_inputs, const float* s_trunk,
    const float* s_in_b, const ushort_t* s_in_wT,
    const float* s2a_b, const ushort_t* s2a_wT,
    const float* xp_w, const float* xp_b, const float* t_feat,
    const float* g, const float* bb,
    const ushort_t* wTl, const float* qb, const float* kb, const float* vb,
    float* a2, ushort_t* q_bf, ushort_t* k_bf, ushort_t* vT_bf){
  __shared__ ushort_t si[16][280];
  __shared__ ushort_t scb[16][408];
  __shared__ float xrow[16][21];
  __shared__ float a_new[16][132];
  __shared__ ushort_t zh[16][152];
  int t = threadIdx.x, lane = t&63, wv = t>>6;
  int rowf = lane&15, kg = lane>>4;
  int bid = blockIdx.x, s_idx = bid/24, lt = bid%24;
  int lr0 = lt*16;

  for(int i=t;i<16*256;i+=256){
    int r=i>>8, c=i&255;
    si[r][c] = f2bf(s_inputs[(size_t)(lr0+r)*256+c]);
  }
  for(int i=t;i<16*21;i+=256){
    int r=i/21, u=i%21;
    xrow[r][u] = x_t[((size_t)s_idx*L + lr0 + r)*21 + u];
  }
  __syncthreads();

  {
    s16x8 af1[8];
    #pragma unroll
    for(int ks=0;ks<8;ks++) af1[ks] = *(const s16x8*)&si[rowf][ks*32+kg*8];
    const float* tf = t_feat + s_idx*384;
    #pragma unroll
    for(int nn=0;nn<6;nn++){
      int col = (wv*6+nn)*16 + rowf;
      float bv = s_in_b[col];
      f32x4 acc = {bv,bv,bv,bv};
      #pragma unroll
      for(int ks=0;ks<8;ks++){
        s16x8 bf = *(const s16x8*)&s_in_wT[col*256 + ks*32 + kg*8];
        acc = __builtin_amdgcn_mfma_f32_16x16x32_bf16(af1[ks], bf, acc, 0,0,0);
      }
      float tfc = tf[col];
      #pragma unroll
      for(int i2=0;i2<4;i2++){
        int r = kg*4+i2;
        scb[r][col] = f2bf(acc[i2] + s_trunk[(size_t)(lr0+r)*384+col] + tfc);
      }
    }
  }
  __syncthreads();

  {
    s16x8 xf[12];
    #pragma unroll
    for(int ks=0;ks<12;ks++) xf[ks] = *(const s16x8*)&scb[rowf][ks*32+kg*8];
    #pragma unroll
    for(int nn=0;nn<2;nn++){
      int col = (wv*2+nn)*16 + rowf;
      float base = xp_b[col] + s2a_b[col];
      f32x4 acc;
      #pragma unroll
      for(int i2=0;i2<4;i2++){
        float xc = base;
        #pragma unroll
        for(int u=0;u<21;u++) xc += xrow[kg*4+i2][u]*xp_w[u*128+col];
        acc[i2] = xc;
      }
      #pragma unroll
      for(int ks=0;ks<12;ks++){
        s16x8 bf = *(const s16x8*)&s2a_wT[col*384 + ks*32 + kg*8];
        acc = __builtin_amdgcn_mfma_f32_16x16x32_bf16(xf[ks], bf, acc, 0,0,0);
      }
      #pragma unroll
      for(int i2=0;i2<4;i2++){
        int r = kg*4+i2;
        a_new[r][col] = acc[i2];
        a2[((size_t)(s_idx*L + lr0 + r))*128 + col] = acc[i2];
      }
    }
  }
  __syncthreads();

  {
    int row = t>>4, sub = t&15;
    const float* xp = &a_new[row][sub*8];
    f32x4 x0 = *(const f32x4*)xp;
    f32x4 x1 = *(const f32x4*)(xp+4);
    float s = x0[0]+x0[1]+x0[2]+x0[3]+x1[0]+x1[1]+x1[2]+x1[3];
    s += __shfl_xor(s,1,64); s += __shfl_xor(s,2,64);
    s += __shfl_xor(s,4,64); s += __shfl_xor(s,8,64);
    float mean = s*(1.f/128.f);
    float q2 = 0.f;
    #pragma unroll
    for(int jj=0;jj<4;jj++){ float d0=x0[jj]-mean, d1=x1[jj]-mean; q2 += d0*d0+d1*d1; }
    q2 += __shfl_xor(q2,1,64); q2 += __shfl_xor(q2,2,64);
    q2 += __shfl_xor(q2,4,64); q2 += __shfl_xor(q2,8,64);
    float rstd = rsqrtf(q2*(1.f/128.f)+1e-5f);
    int c0 = sub*8;
    f32x4 g0 = *(const f32x4*)(g+c0), g1 = *(const f32x4*)(g+c0+4);
    f32x4 b0 = *(const f32x4*)(bb+c0), b1 = *(const f32x4*)(bb+c0+4);
    s16x8 pack;
    #pragma unroll
    for(int jj=0;jj<4;jj++){
      pack[jj]   = (short)f2bf((x0[jj]-mean)*rstd*g0[jj]+b0[jj]);
      pack[jj+4] = (short)f2bf((x1[jj]-mean)*rstd*g1[jj]+b1[jj]);
    }
    *(s16x8*)&zh[row][c0] = pack;
  }
  __syncthreads();
  qkv_project(zh, wTl, qb, kb, vb, q_bf, k_bf, vT_bf, s_idx, lr0, wv, rowf, kg);
}

// ---------------------------------------------------------------------------
// K_fused: 1024 threads / 16 waves. Wave-private bias staging; flash with
// early V loads + 1-chunk K pipeline. flash -> o-proj -> LN -> FFN ->
// next-QKV / out.
// ---------------------------------------------------------------------------
__global__ __launch_bounds__(1024) void k_fused(
    float* a2, const float* an_g, const float* an_b, const ushort_t* wT,
    const float* qb_all, const float* kb_all, const float* vb_all,
    const float* ob_all, const float* f1b_all, const float* f2b_all,
    ushort_t* q_bf, ushort_t* k_bf, ushort_t* vT_bf,
    const ushort_t* bias_all, const float* out_w, const float* out_b,
    float* out, int li){
  __shared__ float orow[16][132];
  __shared__ float ocomb[8][16][20];
  __shared__ float lcomb[8][16];
  union SM {
    struct {
      ushort_t biasw[16][16][200];   // 102,400 B (per-wave slices)
      ushort_t P[16][16][72];        //  36,864 B
    } fl;
    struct {
      float a_new[16][132];
      ushort_t zh[16][152];
      ushort_t h_lds[16][536];
      float fcomb[8][16][20];
    } post;
  };
  __shared__ SM sm;

  int t = threadIdx.x, lane = t&63, wv = t>>6;
  int rowf = lane&15, kg = lane>>4;
  int bid = blockIdx.x, s_idx = bid/24, qt = bid%24;
  int r0 = bid*16;
  const ushort_t* wTl = wT + (size_t)li*WT_LAYER;
  const float* g  = an_g + li*128;
  const float* bb = an_b + li*128;

  // ---- flash: wave = (head h, key-half kh); wave-private bias staging ----
  {
    int h = wv>>1, kh = wv&1;
    int sh = s_idx*NH + h;
    {
      const ushort_t* btile = bias_all + (size_t)(li*24+qt)*8*6144
                            + (size_t)h*16*384 + kh*192;
      #pragma unroll
      for(int it=0; it<6; it++){
        int idx = lane + it*64;
        int row = idx/24, seg = idx%24;
        *(s16x8*)&sm.fl.biasw[wv][row][seg*8] =
            *(const s16x8*)&btile[(size_t)row*384 + seg*8];
      }
    }
    ushort_t (*Pw)[72] = sm.fl.P[wv];
    s16x8 qf = {0,0,0,0,0,0,0,0};
    if(kg < 2) qf = *(const s16x8*)&q_bf[((size_t)sh*384 + qt*16 + rowf)*16 + kg*8];
    const ushort_t* kp = k_bf + (size_t)sh*384*16;
    const ushort_t* vp = vT_bf + ((size_t)sh*16 + rowf)*384;

    f32x4 o0 = {0,0,0,0}, o1 = {0,0,0,0};
    float l_acc = 0.f;

    // prologue: chunk 0 K fragments
    s16x8 kfc[4];
    #pragma unroll
    for(int t4=0;t4<4;t4++){
      kfc[t4] = (s16x8){0,0,0,0,0,0,0,0};
      if(kg < 2) kfc[t4] = *(const s16x8*)&kp[((size_t)(kh*192 + t4*16 + rowf))*16 + kg*8];
    }

    #pragma unroll
    for(int c=0;c<3;c++){
      int key0 = kh*192 + c*64;
      // early V loads (independent of P; land under QK/exp)
      s16x8 vbf0 = *(const s16x8*)&vp[key0 + kg*8];
      s16x8 vbf1 = *(const s16x8*)&vp[key0 + 32 + kg*8];
      // pipeline: next chunk's K fragments
      s16x8 kfn[4];
      if(c < 2){
        #pragma unroll
        for(int t4=0;t4<4;t4++){
          kfn[t4] = (s16x8){0,0,0,0,0,0,0,0};
          if(kg < 2) kfn[t4] = *(const s16x8*)&kp[((size_t)(key0 + 64 + t4*16 + rowf))*16 + kg*8];
        }
      }
      f32x4 st[4];
      #pragma unroll
      for(int t4=0;t4<4;t4++){
        u16x4 bb4 = *(const u16x4*)&sm.fl.biasw[wv][rowf][c*64 + t4*16 + kg*4];
        f32x4 cin;
        #pragma unroll
        for(int jj=0;jj<4;jj++) cin[jj] = bf2f(bb4[jj]);
        st[t4] = __builtin_amdgcn_mfma_f32_16x16x32_bf16(kfc[t4], qf, cin, 0,0,0);
      }
      #pragma unroll
      for(int t4=0;t4<4;t4++){
        float p0 = __expf(st[t4][0]), p1 = __expf(st[t4][1]);
        float p2 = __expf(st[t4][2]), p3 = __expf(st[t4][3]);
        l_acc += (p0+p1)+(p2+p3);
        u16x4 pk = {f2bf(p0), f2bf(p1), f2bf(p2), f2bf(p3)};
        *(u16x4*)&Pw[rowf][t4*16 + kg*4] = pk;
      }
      {
        s16x8 pa = *(const s16x8*)&Pw[rowf][kg*8];
        o0 = __builtin_amdgcn_mfma_f32_16x16x32_bf16(pa, vbf0, o0, 0,0,0);
        s16x8 pb = *(const s16x8*)&Pw[rowf][32 + kg*8];
        o1 = __builtin_amdgcn_mfma_f32_16x16x32_bf16(pb, vbf1, o1, 0,0,0);
      }
      if(c < 2){
        #pragma unroll
        for(int t4=0;t4<4;t4++) kfc[t4] = kfn[t4];
      }
    }
    f32x4 o_acc = o0 + o1;
    l_acc += __shfl_xor(l_acc, 16, 64);
    l_acc += __shfl_xor(l_acc, 32, 64);
    if(kh==1){
      #pragma unroll
      for(int i2=0;i2<4;i2++) ocomb[h][kg*4+i2][rowf] = o_acc[i2];
      if(kg==0) lcomb[h][rowf] = l_acc;
    }
    __syncthreads();
    if(kh==0){
      l_acc += lcomb[h][rowf];
      #pragma unroll
      for(int i2=0;i2<4;i2++) o_acc[i2] += ocomb[h][kg*4+i2][rowf];
      float inv = 1.f / l_acc;
      #pragma unroll
      for(int i2=0;i2<4;i2++){
        float invq = __shfl(inv, kg*4 + i2, 64);
        orow[kg*4+i2][h*16 + rowf] = o_acc[i2]*invq;
      }
    }
  }
  __syncthreads();

  // ---- o-proj + residual -> a_new (waves 0..7) ----
  if(wv < 8){
    s16x8 af[4];
    #pragma unroll
    for(int ks=0;ks<4;ks++){
      f32x4 v0 = *(const f32x4*)&orow[rowf][ks*32+kg*8];
      f32x4 v1 = *(const f32x4*)&orow[rowf][ks*32+kg*8+4];
      s16x8 p;
      #pragma unroll
      for(int jj=0;jj<4;jj++){ p[jj] = (short)f2bf(v0[jj]); p[jj+4] = (short)f2bf(v1[jj]); }
      af[ks] = p;
    }
    const ushort_t* wo = wTl + 180224;
    const float* obp = ob_all + li*128;
    int col = wv*16 + rowf;
    float bv = obp[col];
    f32x4 acc = {bv,bv,bv,bv};
    f32x4 accB = {0,0,0,0};
    #pragma unroll
    for(int ks=0;ks<2;ks++){
      s16x8 bf = *(const s16x8*)&wo[col*128 + ks*32 + kg*8];
      acc = __builtin_amdgcn_mfma_f32_16x16x32_bf16(af[ks], bf, acc, 0,0,0);
      s16x8 bf2 = *(const s16x8*)&wo[col*128 + (ks+2)*32 + kg*8];
      accB = __builtin_amdgcn_mfma_f32_16x16x32_bf16(af[ks+2], bf2, accB, 0,0,0);
    }
    acc += accB;
    #pragma unroll
    for(int i2=0;i2<4;i2++){
      int r = kg*4+i2;
      sm.post.a_new[r][col] = a2[(size_t)(r0+r)*128 + col] + acc[i2];
    }
  }
  __syncthreads();

  // ---- LN (wave wv owns row wv) ----
  {
    int row = wv, c0 = lane*2;
    float x0 = sm.post.a_new[row][c0], x1 = sm.post.a_new[row][c0+1];
    float s = x0+x1;
    s += __shfl_xor(s,1,64); s += __shfl_xor(s,2,64); s += __shfl_xor(s,4,64);
    s += __shfl_xor(s,8,64); s += __shfl_xor(s,16,64); s += __shfl_xor(s,32,64);
    float mean = s*(1.f/128.f);
    float d0=x0-mean, d1=x1-mean;
    float q2 = d0*d0+d1*d1;
    q2 += __shfl_xor(q2,1,64); q2 += __shfl_xor(q2,2,64); q2 += __shfl_xor(q2,4,64);
    q2 += __shfl_xor(q2,8,64); q2 += __shfl_xor(q2,16,64); q2 += __shfl_xor(q2,32,64);
    float rstd = rsqrtf(q2*(1.f/128.f)+1e-5f);
    unsigned int pk = (unsigned int)f2bf(d0*rstd*g[c0]+bb[c0])
                    | ((unsigned int)f2bf(d1*rstd*g[c0+1]+bb[c0+1])<<16);
    *(unsigned int*)&sm.post.zh[row][c0] = pk;
  }
  __syncthreads();

  // ---- FFN GEMM1 + gelu ----
  {
    s16x8 xf[4];
    #pragma unroll
    for(int ks=0;ks<4;ks++) xf[ks] = *(const s16x8*)&sm.post.zh[rowf][ks*32 + kg*8];
    const ushort_t* w1 = wTl + 49152;
    const float* f1bp = f1b_all + li*512;
    #pragma unroll
    for(int nn=0; nn<2; nn++){
      int col = (wv*2+nn)*16 + rowf;
      float bv = f1bp[col];
      f32x4 acc = {bv,bv,bv,bv};
      #pragma unroll
      for(int ks=0;ks<4;ks++){
        s16x8 bf = *(const s16x8*)&w1[col*128 + ks*32 + kg*8];
        acc = __builtin_amdgcn_mfma_f32_16x16x32_bf16(xf[ks], bf, acc, 0,0,0);
      }
      #pragma unroll
      for(int i2=0;i2<4;i2++){
        float x = acc[i2];
        float ge = 0.5f*x*(1.f + erff(x*0.70710678f));
        sm.post.h_lds[kg*4+i2][col] = f2bf(ge);
      }
    }
  }
  __syncthreads();

  // ---- FFN GEMM2 ----
  {
    const ushort_t* w2 = wTl + 114688;
    const float* f2bp = f2b_all + li*128;
    int ct = wv>>1, kh2 = wv&1;
    int col2 = ct*16 + rowf;
    float bv = kh2? 0.f : f2bp[col2];
    f32x4 accA = {bv,bv,bv,bv};
    f32x4 accB = {0,0,0,0};
    int ks0 = kh2*8;
    #pragma unroll
    for(int kk=0; kk<4; kk++){
      s16x8 hfA = *(const s16x8*)&sm.post.h_lds[rowf][(ks0+kk)*32 + kg*8];
      s16x8 bfA = *(const s16x8*)&w2[col2*512 + (ks0+kk)*32 + kg*8];
      accA = __builtin_amdgcn_mfma_f32_16x16x32_bf16(hfA, bfA, accA, 0,0,0);
      s16x8 hfB = *(const s16x8*)&sm.post.h_lds[rowf][(ks0+kk+4)*32 + kg*8];
      s16x8 bfB = *(const s16x8*)&w2[col2*512 + (ks0+kk+4)*32 + kg*8];
      accB = __builtin_amdgcn_mfma_f32_16x16x32_bf16(hfB, bfB, accB, 0,0,0);
    }
    accA += accB;
    if(kh2==1){
      #pragma unroll
      for(int i2=0;i2<4;i2++) sm.post.fcomb[ct][kg*4+i2][rowf] = accA[i2];
    }
    __syncthreads();
    if(kh2==0){
      #pragma unroll
      for(int i2=0;i2<4;i2++){
        int r = kg*4+i2;
        float fin = sm.post.a_new[r][col2] + accA[i2] + sm.post.fcomb[ct][r][rowf];
        a2[(size_t)(r0+r)*128 + col2] = fin;
        sm.post.a_new[r][col2] = fin;
      }
    }
  }
  __syncthreads();

  if(li < NB-1){
    const float* g2  = an_g + (li+1)*128;
    const float* bb2 = an_b + (li+1)*128;
    {
      int row = wv, c0 = lane*2;
      float x0 = sm.post.a_new[row][c0], x1 = sm.post.a_new[row][c0+1];
      float s = x0+x1;
      s += __shfl_xor(s,1,64); s += __shfl_xor(s,2,64); s += __shfl_xor(s,4,64);
      s += __shfl_xor(s,8,64); s += __shfl_xor(s,16,64); s += __shfl_xor(s,32,64);
      float mean = s*(1.f/128.f);
      float d0=x0-mean, d1=x1-mean;
      float q2 = d0*d0+d1*d1;
      q2 += __shfl_xor(q2,1,64); q2 += __shfl_xor(q2,2,64); q2 += __shfl_xor(q2,4,64);
      q2 += __shfl_xor(q2,8,64); q2 += __shfl_xor(q2,16,64); q2 += __shfl_xor(q2,32,64);
      float rstd = rsqrtf(q2*(1.f/128.f)+1e-5f);
      unsigned int pk = (unsigned int)f2bf(d0*rstd*g2[c0]+bb2[c0])
                      | ((unsigned int)f2bf(d1*rstd*g2[c0+1]+bb2[c0+1])<<16);
      *(unsigned int*)&sm.post.zh[row][c0] = pk;
    }
    __syncthreads();
    {
      const ushort_t* wTn = wT + (size_t)(li+1)*WT_LAYER;
      const float* qb2 = qb_all + (li+1)*128;
      const float* kb2 = kb_all + (li+1)*128;
      const float* vb2 = vb_all + (li+1)*128;
      s16x8 af[4];
      #pragma unroll
      for(int ks=0;ks<4;ks++) af[ks] = *(const s16x8*)&sm.post.zh[rowf][ks*32 + kg*8];
      #pragma unroll
      for(int u=0;u<2;u++){
        int unit = wv + u*16;
        if(unit < 24){
          int proj = unit>>3, nt = unit&7;
          int col = nt*16 + rowf;
          const ushort_t* wp = wTn + proj*16384;
          const float* bias = proj==0? qb2 : (proj==1? kb2 : vb2);
          float bv = bias[col];
          f32x4 acc = {bv,bv,bv,bv};
          #pragma unroll
          for(int ks=0;ks<4;ks++){
            s16x8 bf = *(const s16x8*)&wp[col*128 + ks*32 + kg*8];
            acc = __builtin_amdgcn_mfma_f32_16x16x32_bf16(af[ks], bf, acc, 0,0,0);
          }
          int sh = s_idx*NH + nt;
          if(proj==2){
            #pragma unroll
            for(int i2=0;i2<4;i2++)
              vT_bf[((size_t)sh*16 + rowf)*384 + qt*16 + kg*4 + i2] = f2bf(acc[i2]);
          } else {
            float sc = (proj==0)? 0.25f : 1.0f;
            ushort_t* outp = (proj==0)? q_bf : k_bf;
            #pragma unroll
            for(int i2=0;i2<4;i2++)
              outp[((size_t)sh*384 + qt*16 + kg*4 + i2)*16 + rowf] = f2bf(acc[i2]*sc);
          }
        }
      }
    }
  } else {
    for(int idx=t; idx<336; idx+=1024){
      int r = idx/21, c = idx%21;
      float acc = out_b[c];
      #pragma unroll 8
      for(int kk=0;kk<128;kk++) acc += sm.post.a_new[r][kk]*out_w[kk*21+c];
      out[(size_t)(r0+r)*21 + c] = acc;
    }
  }
}

extern "C" void kernel_launch(void* const* d_in, const int* in_sizes, int n_in,
                              void* d_out, int out_size, void* d_ws, size_t ws_size,
                              hipStream_t stream){
  const float* x_t      = (const float*)d_in[0];
  const float* sigma    = (const float*)d_in[1];
  const float* s_inputs = (const float*)d_in[2];
  const float* s_trunk  = (const float*)d_in[3];
  const float* z_trunk  = (const float*)d_in[4];
  const float* s_in_w = (const float*)d_in[6];
  const float* s_in_b = (const float*)d_in[7];
  const float* relp_w = (const float*)d_in[8];
  const float* relp_b = (const float*)d_in[9];
  const float* t1_w = (const float*)d_in[10];
  const float* t1_b = (const float*)d_in[11];
  const float* t2_w = (const float*)d_in[12];
  const float* t2_b = (const float*)d_in[13];
  const float* xp_w = (const float*)d_in[14];
  const float* xp_b = (const float*)d_in[15];
  const float* s2a_w = (const float*)d_in[16];
  const float* s2a_b = (const float*)d_in[17];
  const float* out_w = (const float*)d_in[18];
  const float* out_b = (const float*)d_in[19];
  const float* an_g = (const float*)d_in[20];
  const float* an_b = (const float*)d_in[21];
  const float* zn_g = (const float*)d_in[22];
  const float* zn_b = (const float*)d_in[23];
  const float* qw = (const float*)d_in[24];
  const float* qb = (const float*)d_in[25];
  const float* kw = (const float*)d_in[26];
  const float* kb = (const float*)d_in[27];
  const float* vw = (const float*)d_in[28];
  const float* vb = (const float*)d_in[29];
  const float* zw = (const float*)d_in[30];
  const float* zb = (const float*)d_in[31];
  const float* ow = (const float*)d_in[32];
  const float* ob = (const float*)d_in[33];
  const float* f1w = (const float*)d_in[34];
  const float* f1b = (const float*)d_in[35];
  const float* f2w = (const float*)d_in[36];
  const float* f2b = (const float*)d_in[37];

  float* ws = (float*)d_ws;
  ushort_t* bias_all = (ushort_t*)ws;             // 48*147456 shorts (tile-major)
  float* cb     = ws + (size_t)24*NP;             // 48
  float* t_feat = cb + 48;                        // 768
  float* a2     = t_feat + 768;                   // 98304
  float* rbase  = a2 + (size_t)NS*L*CA;           // 128
  ushort_t* wT      = (ushort_t*)(rbase + 128);   // 6*196608
  ushort_t* wzT     = wT + (size_t)6*WT_LAYER;    // 6144
  ushort_t* q_bf    = wzT + 6144;                 // 98304
  ushort_t* k_bf    = q_bf + 98304;               // 98304
  ushort_t* vT_bf   = k_bf + 98304;               // 98304
  ushort_t* s_in_wT = vT_bf + 98304;              // 98304
  ushort_t* s2a_wT  = s_in_wT + 98304;            // 49152
  float* outp = (float*)d_out;

  k_pre0<<<1,256,0,stream>>>(zn_g,zn_b,zw,zb,relp_w,relp_b,wzT,rbase,cb);
  k_mega<<<2640,256,0,stream>>>(z_trunk,relp_w,rbase,wzT,cb,bias_all,
                                qw,kw,vw,f1w,f2w,ow,s_in_w,s2a_w,
                                wT,s_in_wT,s2a_wT,
                                sigma,t1_w,t1_b,t2_w,t2_b,t_feat);
  k_qkv0<<<48,256,0,stream>>>(x_t,s_inputs,s_trunk,s_in_b,s_in_wT,
                              s2a_b,s2a_wT,xp_w,xp_b,t_feat,
                              an_g, an_b, wT, qb, kb, vb,
                              a2, q_bf, k_bf, vT_bf);
  for(int i=0;i<NB;i++){
    k_fused<<<48,1024,0,stream>>>(a2, an_g, an_b, wT,
        qb, kb, vb, ob, f1b, f2b,
        q_bf, k_bf, vT_bf, bias_all,
        out_w, out_b, outp, i);
  }
}